// Round 1
// baseline (930.171 us; speedup 1.0000x reference)
//
#include <hip/hip_runtime.h>
#include <math.h>

// Problem constants
#define FN 10000      // n_features
#define HN 64         // hidden
#define GN 256        // 4H gates
#define KX 65         // H+1

__device__ __forceinline__ float sigmoidf_(float x) {
    return 1.0f / (1.0f + __expf(-x));
}

// ws layout (floats): [0..63]=Csum, [64..127]=Hsum, [128]=cnt, [129]=any, [130]=tim
__global__ __launch_bounds__(1024) void k_init(const int* __restrict__ mask,
                                               const void* __restrict__ tim_raw,
                                               float* __restrict__ ws, int n) {
    __shared__ int red[16];
    int tid = threadIdx.x;
    int s = 0;
    for (int i = tid; i < n; i += 1024) s += (mask[i] == 1) ? 1 : 0;
    for (int off = 32; off; off >>= 1) s += __shfl_down(s, off);
    int wave = tid >> 6;
    if ((tid & 63) == 0) red[wave] = s;
    __syncthreads();
    if (tid < 128) ws[tid] = 0.0f;   // zero accumulators (ws poisoned each launch)
    if (tid == 0) {
        int tot = 0;
        for (int w = 0; w < 16; ++w) tot += red[w];
        ws[128] = (float)tot;
        ws[129] = (tot > 0) ? 1.0f : 0.0f;
        // tim is a python scalar; decode robustly whether stored as int32 or fp32
        int ti = *(const int*)tim_raw;
        float tf;
        if (ti >= 0 && ti < (1 << 20)) tf = (float)ti;
        else tf = *(const float*)tim_raw;
        ws[130] = tf;
    }
}

__global__ __launch_bounds__(256) void lstm_main(
    const float* __restrict__ X, const int* __restrict__ mask,
    const int* __restrict__ last_occ, const float* __restrict__ Ht,
    const float* __restrict__ c_t,
    const float* __restrict__ W,      // [F,256,65]
    const float* __restrict__ Wb,     // [F,256]
    const float* __restrict__ xT_w, const float* __restrict__ xT_b,   // [F,64]
    const float* __restrict__ delT_w,                                 // [F,128]
    const float* __restrict__ c_inp_w, const float* __restrict__ cf_w,
    const float* __restrict__ c_out_w,                                // [F,64]
    float* __restrict__ ws,           // accumulators + scalars
    float* __restrict__ out)          // [2 + F*64 + 64]
{
    __shared__ float xs[72];               // cur_input [65]
    __shared__ float4 wt4[1040];           // 64 gates x 65 floats (16,640 B)
    __shared__ float gs[GN];               // gates (bias included)
    float* wt = (float*)wt4;

    const int f   = blockIdx.x;
    const int tid = threadIdx.x;

    // stage cur_input = [X[f], Ht[f,:]]
    if (tid < KX) xs[tid] = (tid == 0) ? X[f] : Ht[(size_t)f * HN + (tid - 1)];

    const float* Wf = W + (size_t)f * (GN * KX);
    const int g = tid >> 2;   // 0..63 gate within chunk
    const int p = tid & 3;    // quarter of the dot product

    for (int c = 0; c < 4; ++c) {
        // coalesced float4 staging: chunk base is 16B-aligned (66560*f + 16640*c)
        const float4* src = (const float4*)(Wf + c * (64 * KX));
        for (int i = tid; i < 1040; i += 256) wt4[i] = src[i];
        __syncthreads();

        const float* wrow = wt + g * KX + p * 16;
        const float* xp   = xs + p * 16;
        float acc = 0.0f;
        #pragma unroll
        for (int j = 0; j < 16; ++j) acc += wrow[j] * xp[j];
        if (p == 3) acc += wt[g * KX + 64] * xs[64];
        acc += __shfl_xor(acc, 1);
        acc += __shfl_xor(acc, 2);
        if (p == 0) gs[c * 64 + g] = acc + Wb[(size_t)f * GN + c * 64 + g];
        __syncthreads();
    }

    if (tid < HN) {
        const int h = tid;
        const size_t fh = (size_t)f * HN + h;
        const float anyf  = ws[129];
        const float timf  = ws[130];
        const float delta = timf - (float)last_occ[f];
        const float ct    = c_t[h];
        const float Xf    = xs[0];

        float gi     = sigmoidf_(gs[h]        + c_inp_w[fh] * ct);
        float gf     = sigmoidf_(gs[64 + h]   + cf_w[fh] * ct);
        float go_pre = gs[128 + h];
        float prec   = tanhf(gs[192 + h]);
        float xmT    = xT_w[fh] * Xf + xT_b[fh];
        float dTt    = delT_w[(size_t)f * 2 * HN + h] * delta;
        float dTo    = delT_w[(size_t)f * 2 * HN + HN + h] * delta;
        float Tt     = sigmoidf_(xmT + dTt);
        float aggc   = gf * ct + gi * Tt * prec;
        float go     = sigmoidf_(go_pre + c_out_w[fh] * aggc + dTo);
        float hnew   = go * tanhf(aggc);

        const bool  msk = (mask[f] == 1);
        const float mf  = msk ? 1.0f : 0.0f;
        // H_curr = any ? mf*h_new : Ht   (Ht[f,h] is xs[h+1])
        out[2 + fh] = (anyf > 0.5f) ? (mf * hnew) : xs[h + 1];
        if (msk) {
            atomicAdd(&ws[h], aggc);        // Csum
            atomicAdd(&ws[64 + h], hnew);   // Hsum
        }
    }
}

__global__ __launch_bounds__(256) void k_final(
    const float* __restrict__ ws,
    const float* __restrict__ w1, const float* __restrict__ b1,  // [128,128],[128]
    const float* __restrict__ w2, const float* __restrict__ b2,  // [2,128],[2]
    float* __restrict__ out)
{
    __shared__ float inp[128];
    __shared__ float hid[128];
    const int tid = threadIdx.x;
    const float cnt = fmaxf(ws[128], 1.0f);
    if (tid < 128) inp[tid] = ws[tid] / cnt;           // [C_curr, H_mean]
    if (tid < 64)  out[2 + FN * HN + tid] = ws[tid] / cnt;  // C_curr output
    __syncthreads();

    // hidden = relu(w1 @ inp + b1): 2 lanes per row
    const int i = tid >> 1, half = tid & 1;
    const float* wrow = w1 + i * 128 + half * 64;
    const float* ip   = inp + half * 64;
    float pacc = 0.0f;
    #pragma unroll
    for (int j = 0; j < 64; ++j) pacc += wrow[j] * ip[j];
    pacc += __shfl_xor(pacc, 1);
    if (half == 0) hid[i] = fmaxf(pacc + b1[i], 0.0f);
    __syncthreads();

    if (tid < 64) {
        float p0 = 0.0f, p1 = 0.0f;
        for (int j = tid; j < 128; j += 64) {
            p0 += w2[j] * hid[j];
            p1 += w2[128 + j] * hid[j];
        }
        for (int off = 32; off; off >>= 1) {
            p0 += __shfl_down(p0, off);
            p1 += __shfl_down(p1, off);
        }
        if (tid == 0) {
            float l0 = p0 + b2[0], l1 = p1 + b2[1];
            float m  = fmaxf(l0, l1);
            float e0 = __expf(l0 - m), e1 = __expf(l1 - m);
            out[0] = e0 / (e0 + e1);
            out[1] = e1 / (e0 + e1);
        }
    }
}

extern "C" void kernel_launch(void* const* d_in, const int* in_sizes, int n_in,
                              void* d_out, int out_size, void* d_ws, size_t ws_size,
                              hipStream_t stream) {
    // input order per setup_inputs():
    // 0 tim, 1 X, 2 X_hap, 3 mask, 4 last_occured, 5 Ht, 6 Ct, 7 c_t,
    // 8 lstm_weights, 9 lstm_bias, 10 lstm_xT_weights, 11 lstm_xT_bias,
    // 12 lstm_delT_weights, 13 lstm_c_inp_weights, 14 lstm_cf_weights,
    // 15 lstm_c_out_weights, 16 mlp_w1, 17 mlp_b1, 18 mlp_w2, 19 mlp_b2
    const void*  tim_raw = d_in[0];
    const float* X       = (const float*)d_in[1];
    const int*   mask    = (const int*)d_in[3];
    const int*   last_oc = (const int*)d_in[4];
    const float* Ht      = (const float*)d_in[5];
    const float* c_t     = (const float*)d_in[7];
    const float* W       = (const float*)d_in[8];
    const float* Wb      = (const float*)d_in[9];
    const float* xT_w    = (const float*)d_in[10];
    const float* xT_b    = (const float*)d_in[11];
    const float* delT_w  = (const float*)d_in[12];
    const float* ci_w    = (const float*)d_in[13];
    const float* cf_w    = (const float*)d_in[14];
    const float* co_w    = (const float*)d_in[15];
    const float* w1      = (const float*)d_in[16];
    const float* b1      = (const float*)d_in[17];
    const float* w2      = (const float*)d_in[18];
    const float* b2      = (const float*)d_in[19];

    float* out = (float*)d_out;
    float* ws  = (float*)d_ws;

    k_init<<<1, 1024, 0, stream>>>(mask, tim_raw, ws, FN);
    lstm_main<<<FN, 256, 0, stream>>>(X, mask, last_oc, Ht, c_t, W, Wb,
                                      xT_w, xT_b, delT_w, ci_w, cf_w, co_w,
                                      ws, out);
    k_final<<<1, 256, 0, stream>>>(ws, w1, b1, w2, b2, out);
}

// Round 2
// 898.769 us; speedup vs baseline: 1.0349x; 1.0349x over previous
//
#include <hip/hip_runtime.h>
#include <math.h>

// Problem constants
#define FN 10000      // n_features
#define HN 64         // hidden
#define GN 256        // 4H gates
#define KX 65         // H+1

typedef const __attribute__((address_space(1))) void* gas1_t;
typedef __attribute__((address_space(3))) void* las3_t;

// Async global->LDS, 16B per lane. LDS dest is WAVE-UNIFORM base; HW writes
// lane L at (base + L*16). Global ptr is per-lane.
__device__ __forceinline__ void lds_load16(const void* g, void* l) {
    __builtin_amdgcn_global_load_lds((gas1_t)g, (las3_t)l, 16, 0, 0);
}

__device__ __forceinline__ float sigmoidf_(float x) {
    return 1.0f / (1.0f + __expf(-x));
}

// ws layout (floats): [0..63]=Csum, [64..127]=Hsum, [128]=cnt, [129]=any, [130]=tim
__global__ __launch_bounds__(1024) void k_init(const int* __restrict__ mask,
                                               const void* __restrict__ tim_raw,
                                               float* __restrict__ ws, int n) {
    __shared__ int red[16];
    int tid = threadIdx.x;
    int s = 0;
    for (int i = tid; i < n; i += 1024) s += (mask[i] == 1) ? 1 : 0;
    for (int off = 32; off; off >>= 1) s += __shfl_down(s, off);
    int wave = tid >> 6;
    if ((tid & 63) == 0) red[wave] = s;
    __syncthreads();
    if (tid < 128) ws[tid] = 0.0f;   // zero accumulators (ws poisoned each launch)
    if (tid == 0) {
        int tot = 0;
        for (int w = 0; w < 16; ++w) tot += red[w];
        ws[128] = (float)tot;
        ws[129] = (tot > 0) ? 1.0f : 0.0f;
        int ti = *(const int*)tim_raw;
        float tf;
        if (ti >= 0 && ti < (1 << 20)) tf = (float)ti;
        else tf = *(const float*)tim_raw;
        ws[130] = tf;
    }
}

// One block per feature. Wave w owns gates [c*64 + 16w, c*64 + 16w + 16) for
// each chunk c; each quad (4 lanes) owns one gate row. No __syncthreads:
// every wave stages ONLY its own LDS region via async global_load_lds and
// waits with fine-grained vmcnt.
__global__ __launch_bounds__(256) void lstm_main(
    const float* __restrict__ X, const int* __restrict__ mask,
    const int* __restrict__ last_occ, const float* __restrict__ Ht,
    const float* __restrict__ c_t,
    const float* __restrict__ W,      // [F,256,65]
    const float* __restrict__ Wb,     // [F,256]
    const float* __restrict__ xT_w, const float* __restrict__ xT_b,   // [F,64]
    const float* __restrict__ delT_w,                                 // [F,128]
    const float* __restrict__ c_inp_w, const float* __restrict__ cf_w,
    const float* __restrict__ c_out_w,                                // [F,64]
    const float* __restrict__ ws_in,  // scalars (129=any, 130=tim)
    float* __restrict__ ws,           // accumulators
    float* __restrict__ out)          // [2 + F*64 + 64]
{
    // double buffer: one chunk = 64 gates x 65 floats = 4160 floats (16.6 KB)
    __shared__ float wbuf[2][4160];

    const int f    = blockIdx.x;
    const int tid  = threadIdx.x;
    const int w    = tid >> 6;        // wave 0..3
    const int lane = tid & 63;
    const int q    = lane >> 2;       // quad 0..15 within wave
    const int p    = tid & 3;         // lane within quad
    const int hq   = w * 16 + q;      // hidden unit this quad owns (0..63)

    // cur_input fragment in registers: x[idx], idx = 16p + j
    // x[0] = X[f], x[i] = Ht[f, i-1]
    float xr[16];
    {
        const float* HtF = Ht + (size_t)f * HN;
        #pragma unroll
        for (int j = 0; j < 16; ++j) {
            int idx = p * 16 + j;
            xr[j] = (idx == 0) ? X[f] : HtF[idx - 1];
        }
    }
    const float x64 = Ht[(size_t)f * HN + 63];   // tail element (used by p==3)

    const float4* Wf4 = (const float4*)(W + (size_t)f * (GN * KX)); // 16640 f4
    // wave w's region within chunk c: float4 [c*1040 + w*260, +260)
    // LDS layout: wbuf[buf][w*1040 .. w*1040+1040) holds those floats linearly.

    // issue chunk 0 stage (5 vmem ops/wave)
    {
        const float4* src = Wf4 + w * 260;
        float* dst = &wbuf[0][w * 1040];
        #pragma unroll
        for (int k = 0; k < 4; ++k)
            lds_load16(src + k * 64 + lane, dst + k * 256);
        if (lane < 4) lds_load16(src + 256 + lane, dst + 1024);
    }

    float ga[4];
    #pragma unroll
    for (int c = 0; c < 4; ++c) {
        if (c < 3) {
            // prefetch chunk c+1 into the other buffer (5 vmem ops)
            const float4* src = Wf4 + (c + 1) * 1040 + w * 260;
            float* dst = &wbuf[(c + 1) & 1][w * 1040];
            #pragma unroll
            for (int k = 0; k < 4; ++k)
                lds_load16(src + k * 64 + lane, dst + k * 256);
            if (lane < 4) lds_load16(src + 256 + lane, dst + 1024);
            __builtin_amdgcn_sched_barrier(0);
            // drain everything except the newest 5 (chunk c+1's) -> chunk c ready
            __builtin_amdgcn_s_waitcnt(0x0F75);   // vmcnt(5), lgkm/exp ignored
            __builtin_amdgcn_sched_barrier(0);
        } else {
            __builtin_amdgcn_sched_barrier(0);
            __builtin_amdgcn_s_waitcnt(0x0F70);   // vmcnt(0)
            __builtin_amdgcn_sched_barrier(0);
        }

        // quad q, lane p: dot over floats [16p, 16p+16) of row (w*16+q)
        const float* row = &wbuf[c & 1][w * 1040 + q * 65 + p * 16];
        float acc = 0.0f;
        #pragma unroll
        for (int j = 0; j < 16; ++j) acc += row[j] * xr[j];
        if (p == 3) acc += wbuf[c & 1][w * 1040 + q * 65 + 64] * x64;
        // quad reduction: all 4 lanes end with the full sum
        acc += __shfl_xor(acc, 1);
        acc += __shfl_xor(acc, 2);
        ga[c] = acc;
    }

    // epilogue: one lane per hidden unit
    if (p == 0) {
        const int h = hq;
        const size_t fh = (size_t)f * HN + h;
        const size_t fg = (size_t)f * GN;
        const float b0 = Wb[fg + h];
        const float b1 = Wb[fg + 64 + h];
        const float b2 = Wb[fg + 128 + h];
        const float b3 = Wb[fg + 192 + h];
        const float anyf = ws_in[129];
        const float timf = ws_in[130];
        const float delta = timf - (float)last_occ[f];
        const float ct = c_t[h];
        const float Xf = xr[0];              // p==0 lane holds X[f]

        float gi   = sigmoidf_(ga[0] + b0 + c_inp_w[fh] * ct);
        float gf   = sigmoidf_(ga[1] + b1 + cf_w[fh] * ct);
        float prec = tanhf(ga[3] + b3);
        float xmT  = xT_w[fh] * Xf + xT_b[fh];
        float dTt  = delT_w[(size_t)f * 2 * HN + h] * delta;
        float dTo  = delT_w[(size_t)f * 2 * HN + HN + h] * delta;
        float Tt   = sigmoidf_(xmT + dTt);
        float aggc = gf * ct + gi * Tt * prec;
        float go   = sigmoidf_(ga[2] + b2 + c_out_w[fh] * aggc + dTo);
        float hnew = go * tanhf(aggc);

        const bool msk = (mask[f] == 1);
        out[2 + fh] = (anyf > 0.5f) ? (msk ? hnew : 0.0f) : Ht[fh];
        if (msk) {
            atomicAdd(&ws[h], aggc);         // Csum
            atomicAdd(&ws[64 + h], hnew);    // Hsum
        }
    }
}

__global__ __launch_bounds__(256) void k_final(
    const float* __restrict__ ws,
    const float* __restrict__ w1, const float* __restrict__ b1,  // [128,128],[128]
    const float* __restrict__ w2, const float* __restrict__ b2,  // [2,128],[2]
    float* __restrict__ out)
{
    __shared__ float inp[128];
    __shared__ float hid[128];
    const int tid = threadIdx.x;
    const float cnt = fmaxf(ws[128], 1.0f);
    if (tid < 128) inp[tid] = ws[tid] / cnt;                // [C_curr, H_mean]
    if (tid < 64)  out[2 + FN * HN + tid] = ws[tid] / cnt;  // C_curr output
    __syncthreads();

    const int i = tid >> 1, half = tid & 1;
    const float* wrow = w1 + i * 128 + half * 64;
    const float* ip   = inp + half * 64;
    float pacc = 0.0f;
    #pragma unroll
    for (int j = 0; j < 64; ++j) pacc += wrow[j] * ip[j];
    pacc += __shfl_xor(pacc, 1);
    if (half == 0) hid[i] = fmaxf(pacc + b1[i], 0.0f);
    __syncthreads();

    if (tid < 64) {
        float p0 = 0.0f, p1 = 0.0f;
        for (int j = tid; j < 128; j += 64) {
            p0 += w2[j] * hid[j];
            p1 += w2[128 + j] * hid[j];
        }
        for (int off = 32; off; off >>= 1) {
            p0 += __shfl_down(p0, off);
            p1 += __shfl_down(p1, off);
        }
        if (tid == 0) {
            float l0 = p0 + b2[0], l1 = p1 + b2[1];
            float m  = fmaxf(l0, l1);
            float e0 = __expf(l0 - m), e1 = __expf(l1 - m);
            out[0] = e0 / (e0 + e1);
            out[1] = e1 / (e0 + e1);
        }
    }
}

extern "C" void kernel_launch(void* const* d_in, const int* in_sizes, int n_in,
                              void* d_out, int out_size, void* d_ws, size_t ws_size,
                              hipStream_t stream) {
    const void*  tim_raw = d_in[0];
    const float* X       = (const float*)d_in[1];
    const int*   mask    = (const int*)d_in[3];
    const int*   last_oc = (const int*)d_in[4];
    const float* Ht      = (const float*)d_in[5];
    const float* c_t     = (const float*)d_in[7];
    const float* W       = (const float*)d_in[8];
    const float* Wb      = (const float*)d_in[9];
    const float* xT_w    = (const float*)d_in[10];
    const float* xT_b    = (const float*)d_in[11];
    const float* delT_w  = (const float*)d_in[12];
    const float* ci_w    = (const float*)d_in[13];
    const float* cf_w    = (const float*)d_in[14];
    const float* co_w    = (const float*)d_in[15];
    const float* w1      = (const float*)d_in[16];
    const float* b1      = (const float*)d_in[17];
    const float* w2      = (const float*)d_in[18];
    const float* b2      = (const float*)d_in[19];

    float* out = (float*)d_out;
    float* ws  = (float*)d_ws;

    k_init<<<1, 1024, 0, stream>>>(mask, tim_raw, ws, FN);
    lstm_main<<<FN, 256, 0, stream>>>(X, mask, last_oc, Ht, c_t, W, Wb,
                                      xT_w, xT_b, delT_w, ci_w, cf_w, co_w,
                                      ws, ws, out);
    k_final<<<1, 256, 0, stream>>>(ws, w1, b1, w2, b2, out);
}